// Round 1
// 5757.293 us; speedup vs baseline: 1.0882x; 1.0882x over previous
//
#include <hip/hip_runtime.h>
#include <hip/hip_bf16.h>
#include <stdint.h>

// Problem constants
#define BATCH 64
#define SEQ   2048
#define KDIM  256
#define HIDD  256

#define LOG2E 1.44269504f

typedef __attribute__((ext_vector_type(8))) short short8;
typedef __attribute__((ext_vector_type(4))) float f32x4;
typedef __attribute__((ext_vector_type(2))) unsigned int uint2v;
typedef __attribute__((ext_vector_type(4))) float f32x4v;
typedef __attribute__((ext_vector_type(4))) int int4v;

#define WSCALE 1172.0f                       // w_i8 = rn(w * WSCALE), |w| <= 0.1083
#define DQF    (1.0f / (127.0f * 1172.0f))   // dequant: acc_i32 -> preact fp32
#define DQFS   (-(LOG2E) * DQF)              // pre-scaled dequant, gates i/f/o
#define DQFG   (2.0f * (LOG2E) * DQF)        // pre-scaled dequant, gate g

__device__ __forceinline__ float fexp2(float x) {
#if __has_builtin(__builtin_amdgcn_exp2f)
    return __builtin_amdgcn_exp2f(x);        // raw v_exp_f32
#else
    return exp2f(x);
#endif
}
__device__ __forceinline__ float frcp(float x) {
#if __has_builtin(__builtin_amdgcn_rcpf)
    return __builtin_amdgcn_rcpf(x);         // raw v_rcp_f32
#else
    return 1.0f / x;
#endif
}

__device__ __forceinline__ unsigned short f32_to_bf16_rne(float f) {
    union { float f; uint32_t u; } v; v.f = f;
    uint32_t u = v.u;
    uint32_t r = (u + 0x7FFFu + ((u >> 16) & 1u)) >> 16;
    return (unsigned short)r;
}
__device__ __forceinline__ float bf16_to_f32(unsigned short h) {
    union { float f; uint32_t u; } v; v.u = ((uint32_t)h) << 16;
    return v.f;
}

// ---------------------------------------------------------------------------
// Prep (unchanged):
//  blocks [0,1024):    WT bf16 [n=g*256+j][k] for proj
//  blocks [1024,1028): biascat[1024] = b_i + b_h (fp32)
//  blocks [1028,1092): Wh8 i8 packed in mfma_i32_16x16x64_i8 B-fragment order
// ---------------------------------------------------------------------------
struct PrepArgs {
    const float* Wi[4];
    const float* Wh[4];
    const float* bi[4];
    const float* bh[4];
    unsigned short* WT;    // [1024][256] bf16
    float* biascat;        // [1024] fp32
    int* Wh8;              // 256 KB i8 packed
};

__global__ __launch_bounds__(256) void prep_kernel(PrepArgs a) {
    int blk = blockIdx.x, tid = threadIdx.x;
    if (blk < 1024) {
        int n = blk, g = n >> 8, j = n & 255, k = tid;
        a.WT[(size_t)n * 256 + k] = f32_to_bf16_rne(a.Wi[g][(size_t)k * 256 + j]);
    } else if (blk < 1028) {
        int n = (blk - 1024) * 256 + tid;
        int g = n >> 8, j = n & 255;
        a.biascat[n] = a.bi[g][j] + a.bh[g][j];
    } else if (blk < 1092) {
        int nt = blk - 1028;
        int ks = tid >> 6, L = tid & 63;
        int g = nt >> 4;
        int j = (nt & 15) * 16 + (L & 15);
        int kbase = ks * 64 + (L >> 4) * 16;
        const float* Wg = a.Wh[g];
        int4v outv;
#pragma unroll
        for (int r = 0; r < 4; ++r) {
            uint32_t dw = 0;
#pragma unroll
            for (int b = 0; b < 4; ++b) {
                float wv = Wg[(size_t)(kbase + r * 4 + b) * 256 + j];
                float s = fminf(fmaxf(wv * WSCALE, -127.f), 127.f);
                int q8 = __float2int_rn(s);
                dw |= ((uint32_t)(uint8_t)(int8_t)q8) << (b * 8);
            }
            outv[r] = (int)dw;
        }
        ((int4v*)a.Wh8)[(nt * 4 + ks) * 64 + L] = outv;
    }
}

// ---------------------------------------------------------------------------
// Projection GEMM (unchanged). Psw dword layout:
//   dword = ((t*4+BG)*8 + g*2+jt)*1024 + ((j>>5)*64 + ((b&15)>>2)*16 + (j&15))*2
//           + ((b&3)>>1);  halfword (b&1)
// Stored value is PRE-SCALED: (x@W + bias) * s_g, s_g = -log2e (i/f/o), +2log2e (g).
// ---------------------------------------------------------------------------
__global__ __launch_bounds__(256, 2) void proj_kernel(
        const float* __restrict__ x,
        const unsigned short* __restrict__ WT,
        const float* __restrict__ biascat,
        uint32_t* __restrict__ Psw) {
    const int t    = blockIdx.x >> 1;
    const int half = blockIdx.x & 1;
    const int w    = threadIdx.x >> 6;    // gate
    const int L    = threadIdx.x & 63;

    __shared__ unsigned short xt[32][272];

    {
        const int r = threadIdx.x >> 3;
        const int qq = threadIdx.x & 7;
        const float* xr = x + ((size_t)(half * 32 + r) * SEQ + t) * KDIM;
#pragma unroll
        for (int it = 0; it < 8; ++it) {
            int c = qq * 4 + it * 32;
            f32x4v v = __builtin_nontemporal_load((const f32x4v*)(xr + c));
            xt[r][c + 0] = f32_to_bf16_rne(v.x);
            xt[r][c + 1] = f32_to_bf16_rne(v.y);
            xt[r][c + 2] = f32_to_bf16_rne(v.z);
            xt[r][c + 3] = f32_to_bf16_rne(v.w);
        }
    }
    __syncthreads();

    f32x4 acc[2][16];
#pragma unroll
    for (int m = 0; m < 2; ++m)
#pragma unroll
        for (int nn = 0; nn < 16; ++nn) acc[m][nn] = (f32x4){0.f, 0.f, 0.f, 0.f};

#pragma unroll
    for (int kt = 0; kt < 8; ++kt) {
        const int kc = kt * 32 + ((L >> 4) * 8);
        short8 a0 = *(const short8*)&xt[(L & 15)][kc];
        short8 a1 = *(const short8*)&xt[16 + (L & 15)][kc];
#pragma unroll
        for (int nn = 0; nn < 16; ++nn) {
            const short8 bf = *(const short8*)(WT +
                ((size_t)(w * 256 + nn * 16 + (L & 15))) * 256 + kc);
            acc[0][nn] = __builtin_amdgcn_mfma_f32_16x16x32_bf16(a0, bf, acc[0][nn], 0, 0, 0);
            acc[1][nn] = __builtin_amdgcn_mfma_f32_16x16x32_bf16(a1, bf, acc[1][nn], 0, 0, 0);
        }
    }

    const float sg = (w == 2) ? (2.0f * LOG2E) : (-LOG2E);

#pragma unroll
    for (int mt2 = 0; mt2 < 2; ++mt2) {
        const int bg = half * 2 + mt2;
#pragma unroll
        for (int nn = 0; nn < 16; ++nn) {
            float bv = biascat[w * 256 + nn * 16 + (L & 15)];
            unsigned short r0 = f32_to_bf16_rne((acc[mt2][nn][0] + bv) * sg);
            unsigned short r1 = f32_to_bf16_rne((acc[mt2][nn][1] + bv) * sg);
            unsigned short r2 = f32_to_bf16_rne((acc[mt2][nn][2] + bv) * sg);
            unsigned short r3 = f32_to_bf16_rne((acc[mt2][nn][3] + bv) * sg);
            uint2v pk;
            pk.x = (uint32_t)r0 | ((uint32_t)r1 << 16);
            pk.y = (uint32_t)r2 | ((uint32_t)r3 << 16);
            size_t off_dw = (((size_t)t * 4 + bg) * 8 + (w * 2 + (nn & 1))) * 1024
                          + (size_t)((nn >> 1) * 64 + L) * 2;
            *(uint2v*)(Psw + off_dw) = pk;
        }
    }
}

// ---------------------------------------------------------------------------
// Recurrence v6: SINGLE barrier per step (was 2).
// Key change vs v5: phase-B thread->output mapping is now WAVE-LOCAL to the
// columns the wave's own MFMAs produce:
//   wave w, lane L: row r=L&3, col j0 = w*32 + (L>>2), outputs j0 and j0+16.
// Hence the pl (preact) slice [g][w*32..w*32+32) is written AND read only by
// wave w -> the A->B handoff needs only an intra-wave lgkmcnt(0), no s_barrier.
// The read index collapses to pl[g*1024 + w*128 + o*64 + L] (bank-linear).
// Psw dword for the new mapping is the SAME layout with jt=o:
//   base_g[g] + o*1024 (proj_kernel unchanged). Arithmetic per output is
// bit-identical to v5 -> absmax must be unchanged.
// Waves now run SKEWED between barriers (MFMA of one wave overlaps activation
// VALU of another on the same SIMD); s_setprio(1) wraps the MFMA cluster
// (T5: pays only with role-split waves, which we now have).
// The end-of-step barrier covers all cross-step hazards: h8[(t+1)&1] RAW,
// h8[t&1] WAR, pl WAR (pl is also wave-local + DS pipe is in-order per wave).
// ---------------------------------------------------------------------------
__global__ __launch_bounds__(512, 2) void recur_kernel(
        const int4v* __restrict__ Wh8,
        const uint32_t* __restrict__ Psw,
        float* __restrict__ out) {
    const int wg = blockIdx.x;          // 16 WGs, batches wg*4 .. wg*4+3
    const int w  = threadIdx.x >> 6;    // wave 0..7
    const int L  = threadIdx.x & 63;
    const int T  = threadIdx.x;

    __shared__ __align__(16) char h8[2][16 * 272];   // i8 h, rows 4..15 always 0
    __shared__ __align__(16) int  pl[4 * 256 * 4];   // [g][j][r] raw i32 acc

    // Persistent B-fragments: 8 tiles x 4 ksteps x 16B = 128 VGPR/lane
    int4v wf[8][4];
#pragma unroll
    for (int g = 0; g < 4; ++g)
#pragma unroll
        for (int jt = 0; jt < 2; ++jt) {
            int nt = g * 16 + w * 2 + jt;
#pragma unroll
            for (int ks = 0; ks < 4; ++ks)
                wf[g * 2 + jt][ks] = Wh8[(nt * 4 + ks) * 64 + L];
        }

    // Zero both h8 buffers (8704 B = 544 int4v)
    for (int i = T; i < 544; i += 512) ((int4v*)h8)[i] = (int4v){0, 0, 0, 0};

    // Activation-thread constants (wave-local mapping)
    const int r_act = L & 3;
    const int jj    = L >> 2;            // 0..15
    const int j0    = w * 32 + jj;       // outputs j0 and j0+16
    const int BGq   = wg >> 2, QQ = wg & 3;

    // Psw base: dword(t,g,o) = t*32768 + base_g[g] + o*1024
    int base_g[4];
    {
        int off = (w * 64 + QQ * 16 + jj) * 2 + (r_act >> 1);
#pragma unroll
        for (int g = 0; g < 4; ++g)
            base_g[g] = (BGq * 8 + g * 2) * 1024 + off;
    }

    // Prefetch P for t=0 and t=1
    uint32_t pref[2][8];
#pragma unroll
    for (int s = 0; s < 2; ++s)
#pragma unroll
        for (int o = 0; o < 2; ++o)
#pragma unroll
            for (int g = 0; g < 4; ++g)
                pref[s][o * 4 + g] =
                    Psw[(size_t)s * 32768 + base_g[g] + o * 1024];

    float c_st[2] = {0.f, 0.f}, h_last[2] = {0.f, 0.f};
    const int psh = (r_act & 1) * 16;   // halfword select within P dword

    __syncthreads();

    for (int t = 0; t < SEQ; ++t) {
        // ---- phase A: MFMA ----
        const char* hb = h8[t & 1] + (L & 15) * 272 + (L >> 4) * 16;
        int4v a0 = *(const int4v*)(hb);
        int4v a1 = *(const int4v*)(hb + 64);
        int4v a2 = *(const int4v*)(hb + 128);
        int4v a3 = *(const int4v*)(hb + 192);

        __builtin_amdgcn_s_setprio(1);
        int4v acc[8];
#pragma unroll
        for (int tile = 0; tile < 8; ++tile) {
            int4v c = (int4v){0, 0, 0, 0};
            c = __builtin_amdgcn_mfma_i32_16x16x64_i8(a0, wf[tile][0], c, 0, 0, 0);
            c = __builtin_amdgcn_mfma_i32_16x16x64_i8(a1, wf[tile][1], c, 0, 0, 0);
            c = __builtin_amdgcn_mfma_i32_16x16x64_i8(a2, wf[tile][2], c, 0, 0, 0);
            c = __builtin_amdgcn_mfma_i32_16x16x64_i8(a3, wf[tile][3], c, 0, 0, 0);
            acc[tile] = c;
        }
        __builtin_amdgcn_s_setprio(0);

        // acc regs 0..3 = rows 0..3 for lanes L<16 -> pl[g][j][0..3]
        // (columns [w*32, w*32+32) -- this wave's own phase-B slice)
        if (L < 16) {
#pragma unroll
            for (int g = 0; g < 4; ++g)
#pragma unroll
                for (int jt = 0; jt < 2; ++jt) {
                    int j = w * 32 + jt * 16 + L;
                    *(int4v*)&pl[g * 1024 + j * 4] = acc[g * 2 + jt];
                }
        }

        asm volatile("" ::: "memory");
        __builtin_amdgcn_s_waitcnt(0xC07F);   // lgkmcnt(0): own pl writes landed
        asm volatile("" ::: "memory");
        // NO barrier: pl slice is wave-local, DS pipe is in-order per wave.

        // ---- phase B: activations (all 512 threads, 2 outputs each) ----
        uint32_t myp[8];
#pragma unroll
        for (int i = 0; i < 8; ++i) myp[i] = pref[t & 1][i];
        if (t + 2 < SEQ) {
            const size_t tb = (size_t)(t + 2) * 32768;
#pragma unroll
            for (int o = 0; o < 2; ++o)
#pragma unroll
                for (int g = 0; g < 4; ++g)
                    pref[t & 1][o * 4 + g] = Psw[tb + base_g[g] + o * 1024];
        }

        char* hw = h8[(t + 1) & 1];
#pragma unroll
        for (int o = 0; o < 2; ++o) {
            int aI = pl[0 * 1024 + w * 128 + o * 64 + L];
            int aF = pl[1 * 1024 + w * 128 + o * 64 + L];
            int aG = pl[2 * 1024 + w * 128 + o * 64 + L];
            int aO = pl[3 * 1024 + w * 128 + o * 64 + L];

            float pi = (float)aI * DQFS + bf16_to_f32((unsigned short)(myp[o * 4 + 0] >> psh));
            float pf = (float)aF * DQFS + bf16_to_f32((unsigned short)(myp[o * 4 + 1] >> psh));
            float pg = (float)aG * DQFG + bf16_to_f32((unsigned short)(myp[o * 4 + 2] >> psh));
            float po = (float)aO * DQFS + bf16_to_f32((unsigned short)(myp[o * 4 + 3] >> psh));

            float iv = frcp(1.f + fexp2(pi));           // sigmoid (arg pre-negated)
            float fv = frcp(1.f + fexp2(pf));
            float gv = 1.f - 2.f * frcp(fexp2(pg) + 1.f);  // tanh (arg pre-scaled 2log2e)
            float ov = frcp(1.f + fexp2(po));

            float cn = fv * c_st[o] + iv * gv;
            c_st[o] = cn;
            float th = 1.f - 2.f * frcp(fexp2(cn * (2.0f * LOG2E)) + 1.f);
            float hv = ov * th;
            h_last[o] = hv;

            hw[r_act * 272 + j0 + o * 16] = (char)__float2int_rn(hv * 127.f);
        }

        asm volatile("" ::: "memory");
        __builtin_amdgcn_s_waitcnt(0xC07F);   // lgkmcnt(0) only
        __builtin_amdgcn_s_barrier();         // single per-step barrier
        asm volatile("" ::: "memory");
    }

    // Final outputs: h then c, fp32 [64][256]
#pragma unroll
    for (int o = 0; o < 2; ++o) {
        int b = wg * 4 + r_act;
        int j = j0 + o * 16;
        out[(size_t)b * 256 + j]         = h_last[o];
        out[16384 + (size_t)b * 256 + j] = c_st[o];
    }
}

// ---------------------------------------------------------------------------
// Launch
// ---------------------------------------------------------------------------
extern "C" void kernel_launch(void* const* d_in, const int* in_sizes, int n_in,
                              void* d_out, int out_size, void* d_ws, size_t ws_size,
                              hipStream_t stream) {
    (void)in_sizes; (void)n_in; (void)out_size; (void)ws_size;
    const float* x = (const float*)d_in[0];

    // Workspace carve (~269.2 MB)
    char* ws = (char*)d_ws;
    const size_t PSW_BYTES = (size_t)SEQ * 4 * 8192 * 4;    // 268,435,456 (dwords)
    uint32_t*       Psw     = (uint32_t*)ws;
    unsigned short* WT      = (unsigned short*)(ws + PSW_BYTES);           // 512 KB
    int*            Wh8     = (int*)(ws + PSW_BYTES + 524288);             // 256 KB
    float*          biascat = (float*)(ws + PSW_BYTES + 524288 + 262144);  // 4 KB

    PrepArgs pa;
    pa.Wi[0] = (const float*)d_in[1];  pa.Wh[0] = (const float*)d_in[2];
    pa.bi[0] = (const float*)d_in[3];  pa.bh[0] = (const float*)d_in[4];
    pa.Wi[1] = (const float*)d_in[5];  pa.Wh[1] = (const float*)d_in[6];
    pa.bi[1] = (const float*)d_in[7];  pa.bh[1] = (const float*)d_in[8];
    pa.Wi[2] = (const float*)d_in[9];  pa.Wh[2] = (const float*)d_in[10];
    pa.bi[2] = (const float*)d_in[11]; pa.bh[2] = (const float*)d_in[12];
    pa.Wi[3] = (const float*)d_in[13]; pa.Wh[3] = (const float*)d_in[14];
    pa.bi[3] = (const float*)d_in[15]; pa.bh[3] = (const float*)d_in[16];
    pa.WT = WT; pa.biascat = biascat; pa.Wh8 = Wh8;
    prep_kernel<<<1092, 256, 0, stream>>>(pa);

    proj_kernel<<<4096, 256, 0, stream>>>(x, WT, biascat, Psw);

    recur_kernel<<<16, 512, 0, stream>>>((const int4v*)Wh8, Psw, (float*)d_out);
}

// Round 4
// 3140.113 us; speedup vs baseline: 1.9951x; 1.8335x over previous
//
#include <hip/hip_runtime.h>
#include <hip/hip_bf16.h>
#include <stdint.h>

// Problem constants
#define BATCH 64
#define SEQ   2048
#define KDIM  256
#define HIDD  256

#define LOG2E 1.44269504f

typedef __attribute__((ext_vector_type(8))) short short8;
typedef __attribute__((ext_vector_type(4))) float f32x4;
typedef __attribute__((ext_vector_type(2))) unsigned int uint2v;
typedef __attribute__((ext_vector_type(4))) float f32x4v;
typedef __attribute__((ext_vector_type(4))) int int4v;

#define WSCALE 1172.0f                       // w_i8 = rn(w * WSCALE), |w| <= 0.1083
#define DQF    (1.0f / (127.0f * 1172.0f))   // dequant: acc_i32 -> preact fp32
#define DQFS   (-(LOG2E) * DQF)              // pre-scaled dequant, gates i/f/o
#define DQFG   (2.0f * (LOG2E) * DQF)        // pre-scaled dequant, gate g

__device__ __forceinline__ float fexp2(float x) {
#if __has_builtin(__builtin_amdgcn_exp2f)
    return __builtin_amdgcn_exp2f(x);        // raw v_exp_f32
#else
    return exp2f(x);
#endif
}
__device__ __forceinline__ float frcp(float x) {
#if __has_builtin(__builtin_amdgcn_rcpf)
    return __builtin_amdgcn_rcpf(x);         // raw v_rcp_f32
#else
    return 1.0f / x;
#endif
}

// i8x4 dot product with i32 accumulate (exact, matches MFMA i8 semantics)
__device__ __forceinline__ int dot4(int a, int b, int c) {
#if __has_builtin(__builtin_amdgcn_sdot4)
    return __builtin_amdgcn_sdot4(a, b, c, false);   // v_dot4_i32_i8
#else
    int s = c;
    s += ((a << 24) >> 24) * ((b << 24) >> 24);
    s += ((a << 16) >> 24) * ((b << 16) >> 24);
    s += ((a << 8)  >> 24) * ((b << 8)  >> 24);
    s += (a >> 24) * (b >> 24);
    return s;
#endif
}

__device__ __forceinline__ unsigned short f32_to_bf16_rne(float f) {
    union { float f; uint32_t u; } v; v.f = f;
    uint32_t u = v.u;
    uint32_t r = (u + 0x7FFFu + ((u >> 16) & 1u)) >> 16;
    return (unsigned short)r;
}
__device__ __forceinline__ float bf16_to_f32(unsigned short h) {
    union { float f; uint32_t u; } v; v.u = ((uint32_t)h) << 16;
    return v.f;
}

// ---------------------------------------------------------------------------
// Prep:
//  blocks [0,1024):    WT bf16 [n=g*256+j][k] for proj
//  blocks [1024,1028): biascat[1024] = b_i + b_h (fp32)
//  blocks [1028,1284): Wp2 i8 GEMV pack: dword Wp2[(g*64+kq)*256 + j] holds
//                      rn(Wh[g][4kq+i][j]*WSCALE) in byte i (i=0..3).
//                      Same quantization as the old MFMA pack -> identical math.
// ---------------------------------------------------------------------------
struct PrepArgs {
    const float* Wi[4];
    const float* Wh[4];
    const float* bi[4];
    const float* bh[4];
    unsigned short* WT;    // [1024][256] bf16
    float* biascat;        // [1024] fp32
    int* Wh8;              // 256 KB: the GEMV pack Wp2
};

__global__ __launch_bounds__(256) void prep_kernel(PrepArgs a) {
    int blk = blockIdx.x, tid = threadIdx.x;
    if (blk < 1024) {
        int n = blk, g = n >> 8, j = n & 255, k = tid;
        a.WT[(size_t)n * 256 + k] = f32_to_bf16_rne(a.Wi[g][(size_t)k * 256 + j]);
    } else if (blk < 1028) {
        int n = (blk - 1024) * 256 + tid;
        int g = n >> 8, j = n & 255;
        a.biascat[n] = a.bi[g][j] + a.bh[g][j];
    } else if (blk < 1284) {
        int gq = blk - 1028;           // g*64 + kq
        int g = gq >> 6, kq = gq & 63;
        int j = tid;
        const float* Wg = a.Wh[g];
        uint32_t dw = 0;
#pragma unroll
        for (int i = 0; i < 4; ++i) {
            float wv = Wg[(size_t)(kq * 4 + i) * 256 + j];
            float s = fminf(fmaxf(wv * WSCALE, -127.f), 127.f);
            int q8 = __float2int_rn(s);
            dw |= ((uint32_t)(uint8_t)(int8_t)q8) << (i * 8);
        }
        a.Wh8[gq * 256 + j] = (int)dw;
    }
}

// ---------------------------------------------------------------------------
// Projection GEMM (unchanged). Psw dword layout:
//   dword = ((t*4+BG)*8 + g*2+jt)*1024 + ((j>>5)*64 + ((b&15)>>2)*16 + (j&15))*2
//           + ((b&3)>>1);  halfword (b&1)
// Stored value is PRE-SCALED: (x@W + bias) * s_g, s_g = -log2e (i/f/o), +2log2e (g).
// ---------------------------------------------------------------------------
__global__ __launch_bounds__(256, 2) void proj_kernel(
        const float* __restrict__ x,
        const unsigned short* __restrict__ WT,
        const float* __restrict__ biascat,
        uint32_t* __restrict__ Psw) {
    const int t    = blockIdx.x >> 1;
    const int half = blockIdx.x & 1;
    const int w    = threadIdx.x >> 6;    // gate
    const int L    = threadIdx.x & 63;

    __shared__ unsigned short xt[32][272];

    {
        const int r = threadIdx.x >> 3;
        const int qq = threadIdx.x & 7;
        const float* xr = x + ((size_t)(half * 32 + r) * SEQ + t) * KDIM;
#pragma unroll
        for (int it = 0; it < 8; ++it) {
            int c = qq * 4 + it * 32;
            f32x4v v = __builtin_nontemporal_load((const f32x4v*)(xr + c));
            xt[r][c + 0] = f32_to_bf16_rne(v.x);
            xt[r][c + 1] = f32_to_bf16_rne(v.y);
            xt[r][c + 2] = f32_to_bf16_rne(v.z);
            xt[r][c + 3] = f32_to_bf16_rne(v.w);
        }
    }
    __syncthreads();

    f32x4 acc[2][16];
#pragma unroll
    for (int m = 0; m < 2; ++m)
#pragma unroll
        for (int nn = 0; nn < 16; ++nn) acc[m][nn] = (f32x4){0.f, 0.f, 0.f, 0.f};

#pragma unroll
    for (int kt = 0; kt < 8; ++kt) {
        const int kc = kt * 32 + ((L >> 4) * 8);
        short8 a0 = *(const short8*)&xt[(L & 15)][kc];
        short8 a1 = *(const short8*)&xt[16 + (L & 15)][kc];
#pragma unroll
        for (int nn = 0; nn < 16; ++nn) {
            const short8 bf = *(const short8*)(WT +
                ((size_t)(w * 256 + nn * 16 + (L & 15))) * 256 + kc);
            acc[0][nn] = __builtin_amdgcn_mfma_f32_16x16x32_bf16(a0, bf, acc[0][nn], 0, 0, 0);
            acc[1][nn] = __builtin_amdgcn_mfma_f32_16x16x32_bf16(a1, bf, acc[1][nn], 0, 0, 0);
        }
    }

    const float sg = (w == 2) ? (2.0f * LOG2E) : (-LOG2E);

#pragma unroll
    for (int mt2 = 0; mt2 < 2; ++mt2) {
        const int bg = half * 2 + mt2;
#pragma unroll
        for (int nn = 0; nn < 16; ++nn) {
            float bv = biascat[w * 256 + nn * 16 + (L & 15)];
            unsigned short r0 = f32_to_bf16_rne((acc[mt2][nn][0] + bv) * sg);
            unsigned short r1 = f32_to_bf16_rne((acc[mt2][nn][1] + bv) * sg);
            unsigned short r2 = f32_to_bf16_rne((acc[mt2][nn][2] + bv) * sg);
            unsigned short r3 = f32_to_bf16_rne((acc[mt2][nn][3] + bv) * sg);
            uint2v pk;
            pk.x = (uint32_t)r0 | ((uint32_t)r1 << 16);
            pk.y = (uint32_t)r2 | ((uint32_t)r3 << 16);
            size_t off_dw = (((size_t)t * 4 + bg) * 8 + (w * 2 + (nn & 1))) * 1024
                          + (size_t)((nn >> 1) * 64 + L) * 2;
            *(uint2v*)(Psw + off_dw) = pk;
        }
    }
}

// ---------------------------------------------------------------------------
// Recurrence v7 (2nd resubmit -- Rounds 2 and 3 were container infra failures;
// kernel never executed. Audited 3x: no OOB, no divergent barrier, no spin,
// static register indexing, ~300 VGPR at 1 wave/SIMD).
// i8 GEMV via v_dot4_i32_i8, 64 WGs x 256 threads (1 batch/WG, 4 waves/CU,
// 64 CUs active -- 4x more CUs than the MFMA version).
// Thread j owns hidden column j: its 4 gate weight columns live in 256 VGPRs
// (Wreg[4][64] dwords, statically indexed). Per step:
//   - read packed-i8 h (64 dwords) from LDS via broadcast ds_read_b128
//   - 256 sdot4 -> 4 i32 gate preacts (exact; identical numerics to MFMA i8)
//   - activation IN-LANE (no redistribution, no pl round trip, all lanes busy)
//   - write h[j] as one i8 byte to the other LDS buffer; one __syncthreads.
// Psw layout & proj unchanged; per-(b,j) read index re-derived from the old
// formula (audited: max dword 67,108,863 < 64Mi; Wp2 <= 65,535; out <= 32,767):
//   idx = t*32768 + (b>>4)*8192 + g*2048 + ((j>>4)&1)*1024 + (j>>5)*128
//       + ((b>>2)&3)*32 + (j&15)*2 + ((b&3)>>1);  halfword b&1.
// pref kept scratch-safe via explicit 2-step loop unroll (prefA/prefB).
// ---------------------------------------------------------------------------
__global__ __launch_bounds__(256, 1) void recur_kernel(
        const int* __restrict__ Wp2,
        const uint32_t* __restrict__ Psw,
        float* __restrict__ out) {
    const int b = blockIdx.x;        // batch 0..63
    const int j = threadIdx.x;       // hidden column 0..255
    const int T = threadIdx.x;

    __shared__ __align__(16) int hq[2][64];   // packed i8 h, double-buffered

    // --- resident weights: 256 VGPRs, fully static indexing ---
    int Wreg[4][64];
#pragma unroll
    for (int g = 0; g < 4; ++g)
#pragma unroll
        for (int kq = 0; kq < 64; ++kq)
            Wreg[g][kq] = Wp2[(g * 64 + kq) * 256 + j];   // coalesced

    // zero both h buffers
    if (T < 128) ((int*)hq)[T] = 0;

    const int basec = (b >> 4) * 8192 + ((j >> 4) & 1) * 1024 + (j >> 5) * 128
                    + ((b >> 2) & 3) * 32 + (j & 15) * 2 + ((b & 3) >> 1);
    const int base0 = basec + 0 * 2048;
    const int base1 = basec + 1 * 2048;
    const int base2 = basec + 2 * 2048;
    const int base3 = basec + 3 * 2048;
    const int psh = (b & 1) * 16;    // halfword select (wave-uniform)

    uint32_t prefA[4], prefB[4];
#pragma unroll
    for (int g = 0; g < 4; ++g) {
        prefA[g] = Psw[(size_t)0 * 32768 + basec + g * 2048];
        prefB[g] = Psw[(size_t)1 * 32768 + basec + g * 2048];
    }

    float c_st = 0.f, h_last = 0.f;

    __syncthreads();

#define LSTM_STEP(TT, PREF, HRD, HWR)                                          \
    {                                                                          \
        uint32_t myp0 = PREF[0], myp1 = PREF[1], myp2 = PREF[2],               \
                 myp3 = PREF[3];                                               \
        if ((TT) + 2 < SEQ) {                                                  \
            const size_t tb = (size_t)((TT) + 2) * 32768;                      \
            PREF[0] = Psw[tb + base0];                                         \
            PREF[1] = Psw[tb + base1];                                         \
            PREF[2] = Psw[tb + base2];                                         \
            PREF[3] = Psw[tb + base3];                                         \
        }                                                                      \
        int a0 = 0, a1 = 0, a2 = 0, a3 = 0;                                    \
        const int4v* h4 = (const int4v*)(HRD);                                 \
        _Pragma("unroll")                                                      \
        for (int kq4 = 0; kq4 < 16; ++kq4) {                                   \
            int4v hv4 = h4[kq4];                                               \
            _Pragma("unroll")                                                  \
            for (int r = 0; r < 4; ++r) {                                      \
                int hh = hv4[r];                                               \
                a0 = dot4(hh, Wreg[0][kq4 * 4 + r], a0);                       \
                a1 = dot4(hh, Wreg[1][kq4 * 4 + r], a1);                       \
                a2 = dot4(hh, Wreg[2][kq4 * 4 + r], a2);                       \
                a3 = dot4(hh, Wreg[3][kq4 * 4 + r], a3);                       \
            }                                                                  \
        }                                                                      \
        float pi = (float)a0 * DQFS + bf16_to_f32((unsigned short)(myp0 >> psh)); \
        float pf = (float)a1 * DQFS + bf16_to_f32((unsigned short)(myp1 >> psh)); \
        float pg = (float)a2 * DQFG + bf16_to_f32((unsigned short)(myp2 >> psh)); \
        float po = (float)a3 * DQFS + bf16_to_f32((unsigned short)(myp3 >> psh)); \
        float iv = frcp(1.f + fexp2(pi));                                      \
        float fv = frcp(1.f + fexp2(pf));                                      \
        float gv = 1.f - 2.f * frcp(fexp2(pg) + 1.f);                          \
        float ov = frcp(1.f + fexp2(po));                                      \
        float cn = fv * c_st + iv * gv;                                        \
        c_st = cn;                                                             \
        float th = 1.f - 2.f * frcp(fexp2(cn * (2.0f * LOG2E)) + 1.f);         \
        float hvv = ov * th;                                                   \
        h_last = hvv;                                                          \
        (HWR)[j] = (char)__float2int_rn(hvv * 127.f);                          \
        __syncthreads();                                                       \
    }

    char* h0b = (char*)hq[0];
    char* h1b = (char*)hq[1];

    for (int t = 0; t < SEQ; t += 2) {
        LSTM_STEP(t,     prefA, h0b, h1b);   // even step: read buf0, write buf1
        LSTM_STEP(t + 1, prefB, h1b, h0b);   // odd  step: read buf1, write buf0
    }
#undef LSTM_STEP

    // Final outputs: h then c, fp32 [64][256]
    out[(size_t)b * 256 + j]         = h_last;
    out[16384 + (size_t)b * 256 + j] = c_st;
}

// ---------------------------------------------------------------------------
// Launch
// ---------------------------------------------------------------------------
extern "C" void kernel_launch(void* const* d_in, const int* in_sizes, int n_in,
                              void* d_out, int out_size, void* d_ws, size_t ws_size,
                              hipStream_t stream) {
    (void)in_sizes; (void)n_in; (void)out_size; (void)ws_size;
    const float* x = (const float*)d_in[0];

    // Workspace carve (~269.2 MB)
    char* ws = (char*)d_ws;
    const size_t PSW_BYTES = (size_t)SEQ * 4 * 8192 * 4;    // 268,435,456 (dwords)
    uint32_t*       Psw     = (uint32_t*)ws;
    unsigned short* WT      = (unsigned short*)(ws + PSW_BYTES);           // 512 KB
    int*            Wh8     = (int*)(ws + PSW_BYTES + 524288);             // 256 KB (Wp2)
    float*          biascat = (float*)(ws + PSW_BYTES + 524288 + 262144);  // 4 KB

    PrepArgs pa;
    pa.Wi[0] = (const float*)d_in[1];  pa.Wh[0] = (const float*)d_in[2];
    pa.bi[0] = (const float*)d_in[3];  pa.bh[0] = (const float*)d_in[4];
    pa.Wi[1] = (const float*)d_in[5];  pa.Wh[1] = (const float*)d_in[6];
    pa.bi[1] = (const float*)d_in[7];  pa.bh[1] = (const float*)d_in[8];
    pa.Wi[2] = (const float*)d_in[9];  pa.Wh[2] = (const float*)d_in[10];
    pa.bi[2] = (const float*)d_in[11]; pa.bh[2] = (const float*)d_in[12];
    pa.Wi[3] = (const float*)d_in[13]; pa.Wh[3] = (const float*)d_in[14];
    pa.bi[3] = (const float*)d_in[15]; pa.bh[3] = (const float*)d_in[16];
    pa.WT = WT; pa.biascat = biascat; pa.Wh8 = Wh8;
    prep_kernel<<<1284, 256, 0, stream>>>(pa);

    proj_kernel<<<4096, 256, 0, stream>>>(x, WT, biascat, Psw);

    recur_kernel<<<64, 256, 0, stream>>>((const int*)Wh8, Psw, (float*)d_out);
}

// Round 5
// 2284.410 us; speedup vs baseline: 2.7424x; 1.3746x over previous
//
#include <hip/hip_runtime.h>
#include <hip/hip_bf16.h>
#include <stdint.h>

// Problem constants
#define BATCH 64
#define SEQ   2048
#define KDIM  256
#define HIDD  256

#define LOG2E 1.44269504f

typedef __attribute__((ext_vector_type(8))) short short8;
typedef __attribute__((ext_vector_type(4))) float f32x4;
typedef __attribute__((ext_vector_type(2))) unsigned int uint2v;
typedef __attribute__((ext_vector_type(4))) float f32x4v;
typedef __attribute__((ext_vector_type(4))) int int4v;

#define WSCALE 1172.0f                       // w_i8 = rn(w * WSCALE), |w| <= 0.1083
#define DQF    (1.0f / (127.0f * 1172.0f))   // dequant: acc_i32 -> preact fp32
#define DQFS   (-(LOG2E) * DQF)              // pre-scaled dequant, gates i/f/o
#define DQFG   (2.0f * (LOG2E) * DQF)        // pre-scaled dequant, gate g

__device__ __forceinline__ float fexp2(float x) {
#if __has_builtin(__builtin_amdgcn_exp2f)
    return __builtin_amdgcn_exp2f(x);        // raw v_exp_f32
#else
    return exp2f(x);
#endif
}
__device__ __forceinline__ float frcp(float x) {
#if __has_builtin(__builtin_amdgcn_rcpf)
    return __builtin_amdgcn_rcpf(x);         // raw v_rcp_f32
#else
    return 1.0f / x;
#endif
}

// i8x4 dot product with i32 accumulate (exact, matches MFMA i8 semantics)
__device__ __forceinline__ int dot4(int a, int b, int c) {
#if __has_builtin(__builtin_amdgcn_sdot4)
    return __builtin_amdgcn_sdot4(a, b, c, false);   // v_dot4_i32_i8
#else
    int s = c;
    s += ((a << 24) >> 24) * ((b << 24) >> 24);
    s += ((a << 16) >> 24) * ((b << 16) >> 24);
    s += ((a << 8)  >> 24) * ((b << 8)  >> 24);
    s += (a >> 24) * (b >> 24);
    return s;
#endif
}

__device__ __forceinline__ unsigned short f32_to_bf16_rne(float f) {
    union { float f; uint32_t u; } v; v.f = f;
    uint32_t u = v.u;
    uint32_t r = (u + 0x7FFFu + ((u >> 16) & 1u)) >> 16;
    return (unsigned short)r;
}
__device__ __forceinline__ float bf16_to_f32(unsigned short h) {
    union { float f; uint32_t u; } v; v.u = ((uint32_t)h) << 16;
    return v.f;
}

// ---------------------------------------------------------------------------
// Prep (unchanged):
//  blocks [0,1024):    WT bf16 [n=g*256+j][k] for proj
//  blocks [1024,1028): biascat[1024] = b_i + b_h (fp32)
//  blocks [1028,1284): Wp2 i8 GEMV pack: dword Wp2[(g*64+kq)*256 + j] holds
//                      rn(Wh[g][4kq+i][j]*WSCALE) in byte i (i=0..3).
// ---------------------------------------------------------------------------
struct PrepArgs {
    const float* Wi[4];
    const float* Wh[4];
    const float* bi[4];
    const float* bh[4];
    unsigned short* WT;    // [1024][256] bf16
    float* biascat;        // [1024] fp32
    int* Wh8;              // 256 KB: the GEMV pack Wp2
};

__global__ __launch_bounds__(256) void prep_kernel(PrepArgs a) {
    int blk = blockIdx.x, tid = threadIdx.x;
    if (blk < 1024) {
        int n = blk, g = n >> 8, j = n & 255, k = tid;
        a.WT[(size_t)n * 256 + k] = f32_to_bf16_rne(a.Wi[g][(size_t)k * 256 + j]);
    } else if (blk < 1028) {
        int n = (blk - 1024) * 256 + tid;
        int g = n >> 8, j = n & 255;
        a.biascat[n] = a.bi[g][j] + a.bh[g][j];
    } else if (blk < 1284) {
        int gq = blk - 1028;           // g*64 + kq
        int g = gq >> 6, kq = gq & 63;
        int j = tid;
        const float* Wg = a.Wh[g];
        uint32_t dw = 0;
#pragma unroll
        for (int i = 0; i < 4; ++i) {
            float wv = Wg[(size_t)(kq * 4 + i) * 256 + j];
            float s = fminf(fmaxf(wv * WSCALE, -127.f), 127.f);
            int q8 = __float2int_rn(s);
            dw |= ((uint32_t)(uint8_t)(int8_t)q8) << (i * 8);
        }
        a.Wh8[gq * 256 + j] = (int)dw;
    }
}

// ---------------------------------------------------------------------------
// Projection GEMM (unchanged). Psw dword layout:
//   dword = ((t*4+BG)*8 + g*2+jt)*1024 + ((j>>5)*64 + ((b&15)>>2)*16 + (j&15))*2
//           + ((b&3)>>1);  halfword (b&1)
// Stored value is PRE-SCALED: (x@W + bias) * s_g, s_g = -log2e (i/f/o), +2log2e (g).
// ---------------------------------------------------------------------------
__global__ __launch_bounds__(256, 2) void proj_kernel(
        const float* __restrict__ x,
        const unsigned short* __restrict__ WT,
        const float* __restrict__ biascat,
        uint32_t* __restrict__ Psw) {
    const int t    = blockIdx.x >> 1;
    const int half = blockIdx.x & 1;
    const int w    = threadIdx.x >> 6;    // gate
    const int L    = threadIdx.x & 63;

    __shared__ unsigned short xt[32][272];

    {
        const int r = threadIdx.x >> 3;
        const int qq = threadIdx.x & 7;
        const float* xr = x + ((size_t)(half * 32 + r) * SEQ + t) * KDIM;
#pragma unroll
        for (int it = 0; it < 8; ++it) {
            int c = qq * 4 + it * 32;
            f32x4v v = __builtin_nontemporal_load((const f32x4v*)(xr + c));
            xt[r][c + 0] = f32_to_bf16_rne(v.x);
            xt[r][c + 1] = f32_to_bf16_rne(v.y);
            xt[r][c + 2] = f32_to_bf16_rne(v.z);
            xt[r][c + 3] = f32_to_bf16_rne(v.w);
        }
    }
    __syncthreads();

    f32x4 acc[2][16];
#pragma unroll
    for (int m = 0; m < 2; ++m)
#pragma unroll
        for (int nn = 0; nn < 16; ++nn) acc[m][nn] = (f32x4){0.f, 0.f, 0.f, 0.f};

#pragma unroll
    for (int kt = 0; kt < 8; ++kt) {
        const int kc = kt * 32 + ((L >> 4) * 8);
        short8 a0 = *(const short8*)&xt[(L & 15)][kc];
        short8 a1 = *(const short8*)&xt[16 + (L & 15)][kc];
#pragma unroll
        for (int nn = 0; nn < 16; ++nn) {
            const short8 bf = *(const short8*)(WT +
                ((size_t)(w * 256 + nn * 16 + (L & 15))) * 256 + kc);
            acc[0][nn] = __builtin_amdgcn_mfma_f32_16x16x32_bf16(a0, bf, acc[0][nn], 0, 0, 0);
            acc[1][nn] = __builtin_amdgcn_mfma_f32_16x16x32_bf16(a1, bf, acc[1][nn], 0, 0, 0);
        }
    }

    const float sg = (w == 2) ? (2.0f * LOG2E) : (-LOG2E);

#pragma unroll
    for (int mt2 = 0; mt2 < 2; ++mt2) {
        const int bg = half * 2 + mt2;
#pragma unroll
        for (int nn = 0; nn < 16; ++nn) {
            float bv = biascat[w * 256 + nn * 16 + (L & 15)];
            unsigned short r0 = f32_to_bf16_rne((acc[mt2][nn][0] + bv) * sg);
            unsigned short r1 = f32_to_bf16_rne((acc[mt2][nn][1] + bv) * sg);
            unsigned short r2 = f32_to_bf16_rne((acc[mt2][nn][2] + bv) * sg);
            unsigned short r3 = f32_to_bf16_rne((acc[mt2][nn][3] + bv) * sg);
            uint2v pk;
            pk.x = (uint32_t)r0 | ((uint32_t)r1 << 16);
            pk.y = (uint32_t)r2 | ((uint32_t)r3 << 16);
            size_t off_dw = (((size_t)t * 4 + bg) * 8 + (w * 2 + (nn & 1))) * 1024
                          + (size_t)((nn >> 1) * 64 + L) * 2;
            *(uint2v*)(Psw + off_dw) = pk;
        }
    }
}

// ---------------------------------------------------------------------------
// Recurrence v8: K-SPLIT GEMV. 64 WGs x 512 threads (1 batch/WG, 8 waves,
// 2 waves/SIMD -- TLP restored). Lane pair (2j, 2j+1) owns hidden column j:
//   thread T: j = T>>1, kh = T&1; holds Wreg[4][32] = 128 VGPRs (the kh K-half
//   of its 4 gate weight columns) -> total reg demand ~190, fits the 256-VGPR
//   cap at 2 waves/SIMD (__launch_bounds__(512,2)) WITHOUT AGPR traffic.
//   (Round-4 post-mortem: Wreg[4][64]=256 regs forced AGPR residency at
//    VGPR_Count=144, adding ~256 accvgpr_read/step and pinning 1 wave/SIMD.)
// Per step: 128 dot4 -> 4 partial preacts; combine with 4x __shfl_xor(a,1)
// (integer add, bit-exact same totals as v7); activation computed by both
// lanes of the pair (uniform, no divergence); kh==0 lane writes h byte.
// Psw: both lanes of a pair read the same 4 dwords (hardware-merged).
// ---------------------------------------------------------------------------
__global__ __launch_bounds__(512, 2) void recur_kernel(
        const int* __restrict__ Wp2,
        const uint32_t* __restrict__ Psw,
        float* __restrict__ out) {
    const int b  = blockIdx.x;        // batch 0..63
    const int T  = threadIdx.x;       // 0..511
    const int j  = T >> 1;            // hidden column 0..255
    const int kh = T & 1;             // K-half 0..1

    __shared__ __align__(16) int hq[2][64];   // packed i8 h, double-buffered

    // --- resident weights: 128 VGPRs, fully static indexing ---
    int Wreg[4][32];
#pragma unroll
    for (int g = 0; g < 4; ++g)
#pragma unroll
        for (int kq = 0; kq < 32; ++kq)
            Wreg[g][kq] = Wp2[(g * 64 + kh * 32 + kq) * 256 + j];

    // zero both h buffers (128 dwords)
    if (T < 128) ((int*)hq)[T] = 0;

    // Psw dword index (same derivation as v7; audited vs proj layout):
    // idx = t*32768 + (b>>4)*8192 + g*2048 + ((j>>4)&1)*1024 + (j>>5)*128
    //     + ((b>>2)&3)*32 + (j&15)*2 + ((b&3)>>1);  halfword b&1.
    const int basec = (b >> 4) * 8192 + ((j >> 4) & 1) * 1024 + (j >> 5) * 128
                    + ((b >> 2) & 3) * 32 + (j & 15) * 2 + ((b & 3) >> 1);
    const int base0 = basec + 0 * 2048;
    const int base1 = basec + 1 * 2048;
    const int base2 = basec + 2 * 2048;
    const int base3 = basec + 3 * 2048;
    const int psh = (b & 1) * 16;    // halfword select (kernel-uniform)

    uint32_t prefA[4], prefB[4];
#pragma unroll
    for (int g = 0; g < 4; ++g) {
        prefA[g] = Psw[(size_t)0 * 32768 + basec + g * 2048];
        prefB[g] = Psw[(size_t)1 * 32768 + basec + g * 2048];
    }

    float c_st = 0.f, h_last = 0.f;

    __syncthreads();

#define LSTM_STEP(TT, PREF, HRD, HWR)                                          \
    {                                                                          \
        uint32_t myp0 = PREF[0], myp1 = PREF[1], myp2 = PREF[2],               \
                 myp3 = PREF[3];                                               \
        if ((TT) + 2 < SEQ) {                                                  \
            const size_t tb = (size_t)((TT) + 2) * 32768;                      \
            PREF[0] = Psw[tb + base0];                                         \
            PREF[1] = Psw[tb + base1];                                         \
            PREF[2] = Psw[tb + base2];                                         \
            PREF[3] = Psw[tb + base3];                                         \
        }                                                                      \
        int a0 = 0, a1 = 0, a2 = 0, a3 = 0;                                    \
        const int4v* h4 = (const int4v*)((HRD) + kh * 128);                    \
        _Pragma("unroll")                                                      \
        for (int kq4 = 0; kq4 < 8; ++kq4) {                                    \
            int4v hv4 = h4[kq4];                                               \
            _Pragma("unroll")                                                  \
            for (int r = 0; r < 4; ++r) {                                      \
                int hh = hv4[r];                                               \
                a0 = dot4(hh, Wreg[0][kq4 * 4 + r], a0);                       \
                a1 = dot4(hh, Wreg[1][kq4 * 4 + r], a1);                       \
                a2 = dot4(hh, Wreg[2][kq4 * 4 + r], a2);                       \
                a3 = dot4(hh, Wreg[3][kq4 * 4 + r], a3);                       \
            }                                                                  \
        }                                                                      \
        a0 += __shfl_xor(a0, 1, 64);  /* combine K-halves: integer, exact */   \
        a1 += __shfl_xor(a1, 1, 64);                                           \
        a2 += __shfl_xor(a2, 1, 64);                                           \
        a3 += __shfl_xor(a3, 1, 64);                                           \
        float pi = (float)a0 * DQFS + bf16_to_f32((unsigned short)(myp0 >> psh)); \
        float pf = (float)a1 * DQFS + bf16_to_f32((unsigned short)(myp1 >> psh)); \
        float pg = (float)a2 * DQFG + bf16_to_f32((unsigned short)(myp2 >> psh)); \
        float po = (float)a3 * DQFS + bf16_to_f32((unsigned short)(myp3 >> psh)); \
        float iv = frcp(1.f + fexp2(pi));                                      \
        float fv = frcp(1.f + fexp2(pf));                                      \
        float gv = 1.f - 2.f * frcp(fexp2(pg) + 1.f);                          \
        float ov = frcp(1.f + fexp2(po));                                      \
        float cn = fv * c_st + iv * gv;                                        \
        c_st = cn;                                                             \
        float th = 1.f - 2.f * frcp(fexp2(cn * (2.0f * LOG2E)) + 1.f);         \
        float hvv = ov * th;                                                   \
        h_last = hvv;                                                          \
        if (kh == 0) (HWR)[j] = (char)__float2int_rn(hvv * 127.f);             \
        __syncthreads();                                                       \
    }

    char* h0b = (char*)hq[0];
    char* h1b = (char*)hq[1];

    for (int t = 0; t < SEQ; t += 2) {
        LSTM_STEP(t,     prefA, h0b, h1b);   // even step: read buf0, write buf1
        LSTM_STEP(t + 1, prefB, h1b, h0b);   // odd  step: read buf1, write buf0
    }
#undef LSTM_STEP

    // Final outputs: h then c, fp32 [64][256]
    if (kh == 0) {
        out[(size_t)b * 256 + j]         = h_last;
        out[16384 + (size_t)b * 256 + j] = c_st;
    }
}

// ---------------------------------------------------------------------------
// Launch
// ---------------------------------------------------------------------------
extern "C" void kernel_launch(void* const* d_in, const int* in_sizes, int n_in,
                              void* d_out, int out_size, void* d_ws, size_t ws_size,
                              hipStream_t stream) {
    (void)in_sizes; (void)n_in; (void)out_size; (void)ws_size;
    const float* x = (const float*)d_in[0];

    // Workspace carve (~269.2 MB)
    char* ws = (char*)d_ws;
    const size_t PSW_BYTES = (size_t)SEQ * 4 * 8192 * 4;    // 268,435,456 (dwords)
    uint32_t*       Psw     = (uint32_t*)ws;
    unsigned short* WT      = (unsigned short*)(ws + PSW_BYTES);           // 512 KB
    int*            Wh8     = (int*)(ws + PSW_BYTES + 524288);             // 256 KB (Wp2)
    float*          biascat = (float*)(ws + PSW_BYTES + 524288 + 262144);  // 4 KB

    PrepArgs pa;
    pa.Wi[0] = (const float*)d_in[1];  pa.Wh[0] = (const float*)d_in[2];
    pa.bi[0] = (const float*)d_in[3];  pa.bh[0] = (const float*)d_in[4];
    pa.Wi[1] = (const float*)d_in[5];  pa.Wh[1] = (const float*)d_in[6];
    pa.bi[1] = (const float*)d_in[7];  pa.bh[1] = (const float*)d_in[8];
    pa.Wi[2] = (const float*)d_in[9];  pa.Wh[2] = (const float*)d_in[10];
    pa.bi[2] = (const float*)d_in[11]; pa.bh[2] = (const float*)d_in[12];
    pa.Wi[3] = (const float*)d_in[13]; pa.Wh[3] = (const float*)d_in[14];
    pa.bi[3] = (const float*)d_in[15]; pa.bh[3] = (const float*)d_in[16];
    pa.WT = WT; pa.biascat = biascat; pa.Wh8 = Wh8;
    prep_kernel<<<1284, 256, 0, stream>>>(pa);

    proj_kernel<<<4096, 256, 0, stream>>>(x, WT, biascat, Psw);

    recur_kernel<<<64, 512, 0, stream>>>((const int*)Wh8, Psw, (float*)d_out);
}

// Round 6
// 2046.381 us; speedup vs baseline: 3.0614x; 1.1163x over previous
//
#include <hip/hip_runtime.h>
#include <hip/hip_bf16.h>
#include <stdint.h>

// Problem constants
#define BATCH 64
#define SEQ   2048
#define KDIM  256
#define HIDD  256

#define LOG2E 1.44269504f

typedef __attribute__((ext_vector_type(8))) short short8;
typedef __attribute__((ext_vector_type(4))) float f32x4;
typedef __attribute__((ext_vector_type(2))) unsigned int uint2v;
typedef __attribute__((ext_vector_type(4))) float f32x4v;
typedef __attribute__((ext_vector_type(4))) int int4v;

#define WSCALE 1172.0f                       // w_i8 = rn(w * WSCALE), |w| <= 0.1083
#define DQF    (1.0f / (127.0f * 1172.0f))   // dequant: acc_i32 -> preact fp32
#define DQFS   (-(LOG2E) * DQF)              // pre-scaled dequant, gates i/f/o
#define DQFG2  (-2.0f * (LOG2E) * DQF)       // pre-scaled dequant, gate g (NEW: -2log2e)
#define CNEG   (-2.0f * LOG2E)               // tanh(c) via 2*sigma(2c)-1

__device__ __forceinline__ float fexp2(float x) {
#if __has_builtin(__builtin_amdgcn_exp2f)
    return __builtin_amdgcn_exp2f(x);        // raw v_exp_f32
#else
    return exp2f(x);
#endif
}
__device__ __forceinline__ float frcp(float x) {
#if __has_builtin(__builtin_amdgcn_rcpf)
    return __builtin_amdgcn_rcpf(x);         // raw v_rcp_f32
#else
    return 1.0f / x;
#endif
}

// i8x4 dot product with i32 accumulate (exact)
__device__ __forceinline__ int dot4(int a, int b, int c) {
#if __has_builtin(__builtin_amdgcn_sdot4)
    return __builtin_amdgcn_sdot4(a, b, c, false);   // v_dot4_i32_i8
#else
    int s = c;
    s += ((a << 24) >> 24) * ((b << 24) >> 24);
    s += ((a << 16) >> 24) * ((b << 16) >> 24);
    s += ((a << 8)  >> 24) * ((b << 8)  >> 24);
    s += (a >> 24) * (b >> 24);
    return s;
#endif
}

// Quad-perm DPP cross-lane (VALU pipe, not LDS): lane L <-> L^1 / L^2.
// quad_perm [1,0,3,2] = 0xB1 (xor1); [2,3,0,1] = 0x4E (xor2).
#if __has_builtin(__builtin_amdgcn_update_dpp)
#define XOR1_I(x) __builtin_amdgcn_update_dpp(0, (x), 0xB1, 0xF, 0xF, true)
#define XOR2_I(x) __builtin_amdgcn_update_dpp(0, (x), 0x4E, 0xF, 0xF, true)
#else
#define XOR1_I(x) __shfl_xor((x), 1, 64)
#define XOR2_I(x) __shfl_xor((x), 2, 64)
#endif
__device__ __forceinline__ float xor1_f(float x) {
    return __int_as_float(XOR1_I(__float_as_int(x)));
}
__device__ __forceinline__ float xor2_f(float x) {
    return __int_as_float(XOR2_I(__float_as_int(x)));
}

__device__ __forceinline__ unsigned short f32_to_bf16_rne(float f) {
    union { float f; uint32_t u; } v; v.f = f;
    uint32_t u = v.u;
    uint32_t r = (u + 0x7FFFu + ((u >> 16) & 1u)) >> 16;
    return (unsigned short)r;
}
__device__ __forceinline__ float bf16_to_f32(unsigned short h) {
    union { float f; uint32_t u; } v; v.u = ((uint32_t)h) << 16;
    return v.f;
}

// ---------------------------------------------------------------------------
// Prep (unchanged layout):
//  blocks [0,1024):    WT bf16 [n=g*256+j][k] for proj
//  blocks [1024,1028): biascat[1024] = b_i + b_h (fp32)
//  blocks [1028,1284): Wp2 i8 GEMV pack: dword Wp2[(g*64+kq)*256 + j] holds
//                      rn(Wh[g][4kq+i][j]*WSCALE) in byte i (i=0..3).
// ---------------------------------------------------------------------------
struct PrepArgs {
    const float* Wi[4];
    const float* Wh[4];
    const float* bi[4];
    const float* bh[4];
    unsigned short* WT;    // [1024][256] bf16
    float* biascat;        // [1024] fp32
    int* Wh8;              // 256 KB: the GEMV pack Wp2
};

__global__ __launch_bounds__(256) void prep_kernel(PrepArgs a) {
    int blk = blockIdx.x, tid = threadIdx.x;
    if (blk < 1024) {
        int n = blk, g = n >> 8, j = n & 255, k = tid;
        a.WT[(size_t)n * 256 + k] = f32_to_bf16_rne(a.Wi[g][(size_t)k * 256 + j]);
    } else if (blk < 1028) {
        int n = (blk - 1024) * 256 + tid;
        int g = n >> 8, j = n & 255;
        a.biascat[n] = a.bi[g][j] + a.bh[g][j];
    } else if (blk < 1284) {
        int gq = blk - 1028;           // g*64 + kq
        int g = gq >> 6, kq = gq & 63;
        int j = tid;
        const float* Wg = a.Wh[g];
        uint32_t dw = 0;
#pragma unroll
        for (int i = 0; i < 4; ++i) {
            float wv = Wg[(size_t)(kq * 4 + i) * 256 + j];
            float s = fminf(fmaxf(wv * WSCALE, -127.f), 127.f);
            int q8 = __float2int_rn(s);
            dw |= ((uint32_t)(uint8_t)(int8_t)q8) << (i * 8);
        }
        a.Wh8[gq * 256 + j] = (int)dw;
    }
}

// ---------------------------------------------------------------------------
// Projection GEMM. Psw dword layout (unchanged):
//   dword = ((t*4+BG)*8 + g*2+jt)*1024 + ((j>>5)*64 + ((b&15)>>2)*16 + (j&15))*2
//           + ((b&3)>>1);  halfword (b&1)
// Stored value PRE-SCALED: (x@W + bias) * s_g.
// CHANGE vs R5: gate g now uses s_g = -2*log2e (was +2*log2e) so ALL gates are
// sigmoid-form in recur: sig = rcp(1+exp2(p)); tanh = 2*sig - 1.
// ---------------------------------------------------------------------------
__global__ __launch_bounds__(256, 2) void proj_kernel(
        const float* __restrict__ x,
        const unsigned short* __restrict__ WT,
        const float* __restrict__ biascat,
        uint32_t* __restrict__ Psw) {
    const int t    = blockIdx.x >> 1;
    const int half = blockIdx.x & 1;
    const int w    = threadIdx.x >> 6;    // gate
    const int L    = threadIdx.x & 63;

    __shared__ unsigned short xt[32][272];

    {
        const int r = threadIdx.x >> 3;
        const int qq = threadIdx.x & 7;
        const float* xr = x + ((size_t)(half * 32 + r) * SEQ + t) * KDIM;
#pragma unroll
        for (int it = 0; it < 8; ++it) {
            int c = qq * 4 + it * 32;
            f32x4v v = __builtin_nontemporal_load((const f32x4v*)(xr + c));
            xt[r][c + 0] = f32_to_bf16_rne(v.x);
            xt[r][c + 1] = f32_to_bf16_rne(v.y);
            xt[r][c + 2] = f32_to_bf16_rne(v.z);
            xt[r][c + 3] = f32_to_bf16_rne(v.w);
        }
    }
    __syncthreads();

    f32x4 acc[2][16];
#pragma unroll
    for (int m = 0; m < 2; ++m)
#pragma unroll
        for (int nn = 0; nn < 16; ++nn) acc[m][nn] = (f32x4){0.f, 0.f, 0.f, 0.f};

#pragma unroll
    for (int kt = 0; kt < 8; ++kt) {
        const int kc = kt * 32 + ((L >> 4) * 8);
        short8 a0 = *(const short8*)&xt[(L & 15)][kc];
        short8 a1 = *(const short8*)&xt[16 + (L & 15)][kc];
#pragma unroll
        for (int nn = 0; nn < 16; ++nn) {
            const short8 bf = *(const short8*)(WT +
                ((size_t)(w * 256 + nn * 16 + (L & 15))) * 256 + kc);
            acc[0][nn] = __builtin_amdgcn_mfma_f32_16x16x32_bf16(a0, bf, acc[0][nn], 0, 0, 0);
            acc[1][nn] = __builtin_amdgcn_mfma_f32_16x16x32_bf16(a1, bf, acc[1][nn], 0, 0, 0);
        }
    }

    const float sg = (w == 2) ? (-2.0f * LOG2E) : (-LOG2E);

#pragma unroll
    for (int mt2 = 0; mt2 < 2; ++mt2) {
        const int bg = half * 2 + mt2;
#pragma unroll
        for (int nn = 0; nn < 16; ++nn) {
            float bv = biascat[w * 256 + nn * 16 + (L & 15)];
            unsigned short r0 = f32_to_bf16_rne((acc[mt2][nn][0] + bv) * sg);
            unsigned short r1 = f32_to_bf16_rne((acc[mt2][nn][1] + bv) * sg);
            unsigned short r2 = f32_to_bf16_rne((acc[mt2][nn][2] + bv) * sg);
            unsigned short r3 = f32_to_bf16_rne((acc[mt2][nn][3] + bv) * sg);
            uint2v pk;
            pk.x = (uint32_t)r0 | ((uint32_t)r1 << 16);
            pk.y = (uint32_t)r2 | ((uint32_t)r3 << 16);
            size_t off_dw = (((size_t)t * 4 + bg) * 8 + (w * 2 + (nn & 1))) * 1024
                          + (size_t)((nn >> 1) * 64 + L) * 2;
            *(uint2v*)(Psw + off_dw) = pk;
        }
    }
}

// ---------------------------------------------------------------------------
// Recurrence v9: QUAD-PER-COLUMN GEMV. 64 WGs x 1024 threads (1 batch/WG,
// 16 waves = 4 waves/SIMD). Lane quad owns column j = T>>2; lane q = T&3:
//   Wreg[m][kq] = Wp2[((q^m)*64 + q*16 + kq)*256 + j]  (64 VGPRs; gate q^m,
//   K-quarter q) -- total reg demand ~90 <= 128 cap at (1024,4): no AGPRs.
//   (R5 post-mortem: compiler AGPR-ified the 128-reg Wreg at VGPR_Count=88,
//    inflating VALU busy ~2x over the clean-issue model.)
// Per step per thread: 4x ds_read_b128 (own K-quarter of packed h; 2-way bank
// aliasing = free), 64 dot4 -> partials p_m for gate q^m.
// Reduce-scatter butterfly in DPP (VALU pipe, 3 shuffles, 0 selects):
//   f0 = (p0 + xor1(p1)) + xor2(p2 + xor1(p3))  ==  FULL K=256 sum of gate q.
//   [proof: p_m(lane k) = gate k^m over quarter k; r0 = gate q over {q,q^1};
//    r2 = gate q^2 over {q,q^1}; xor2(r2) = gate q over {q^2,q^3}.]
// Integer adds -> bit-exact same preacts as R5. One Psw load/thread/step
// (own gate only). Activation: single sigmoid-form per lane (proj pre-scales
// gate g by -2log2e; tanh = 2*sig-1). Cross-lane c/h chain via 3 DPP:
//   m = v*xor2(v)   [lane0: i*g]
//   cn = v*c + xor1(m)  [lane1: f*c + i*g]  -> th = 2*sig(2cn)-1 [lane1]
//   h  = v*xor2(th)  [lane3: o*tanh(c)] -> lane3 writes h byte, lane1 owns c.
// ---------------------------------------------------------------------------
__global__ __launch_bounds__(1024, 4) void recur_kernel(
        const int* __restrict__ Wp2,
        const uint32_t* __restrict__ Psw,
        float* __restrict__ out) {
    const int b = blockIdx.x;        // batch 0..63
    const int T = threadIdx.x;       // 0..1023
    const int j = T >> 2;            // hidden column 0..255
    const int q = T & 3;             // lane role: gate q, K-quarter q

    __shared__ __align__(16) int hq[2][64];   // packed i8 h, double-buffered

    // --- resident weights: 64 VGPRs, fully static indexing ---
    int Wreg[4][16];
#pragma unroll
    for (int m = 0; m < 4; ++m)
#pragma unroll
        for (int kq = 0; kq < 16; ++kq)
            Wreg[m][kq] = Wp2[((q ^ m) * 64 + q * 16 + kq) * 256 + j];

    // zero both h buffers (128 dwords)
    if (T < 128) ((int*)hq)[T] = 0;

    // Psw dword index for THIS lane's gate q (same layout derivation as R4/R5):
    // idx = t*32768 + (b>>4)*8192 + q*2048 + ((j>>4)&1)*1024 + (j>>5)*128
    //     + ((b>>2)&3)*32 + (j&15)*2 + ((b&3)>>1);  halfword b&1.
    const int baseq = (b >> 4) * 8192 + q * 2048 + ((j >> 4) & 1) * 1024
                    + (j >> 5) * 128 + ((b >> 2) & 3) * 32 + (j & 15) * 2
                    + ((b & 3) >> 1);
    const int psh = (b & 1) * 16;    // halfword select (WG-uniform)

    uint32_t prefA = Psw[baseq];             // t=0
    uint32_t prefB = Psw[32768 + baseq];     // t=1

    // lane-role constants
    const float dqf  = (q == 2) ? DQFG2 : DQFS;
    const float vsc  = (q == 2) ? 2.f : 1.f;   // tanh = 2*sig - 1 for gate g
    const float voff = (q == 2) ? -1.f : 0.f;

    float c_st = 0.f, h_last = 0.f;

    __syncthreads();

#define LSTM_STEP(TT, PREF, HRD, HWR)                                          \
    {                                                                          \
        uint32_t myp = PREF;                                                   \
        if ((TT) + 2 < SEQ)                                                    \
            PREF = Psw[(size_t)((TT) + 2) * 32768 + baseq];                    \
        int p0 = 0, p1 = 0, p2 = 0, p3 = 0;                                    \
        const int4v* h4 = (const int4v*)((HRD) + q * 16);                      \
        _Pragma("unroll")                                                      \
        for (int k4 = 0; k4 < 4; ++k4) {                                       \
            int4v hb = h4[k4];                                                 \
            _Pragma("unroll")                                                  \
            for (int r = 0; r < 4; ++r) {                                      \
                int hh = hb[r];                                                \
                p0 = dot4(hh, Wreg[0][k4 * 4 + r], p0);                        \
                p1 = dot4(hh, Wreg[1][k4 * 4 + r], p1);                        \
                p2 = dot4(hh, Wreg[2][k4 * 4 + r], p2);                        \
                p3 = dot4(hh, Wreg[3][k4 * 4 + r], p3);                        \
            }                                                                  \
        }                                                                      \
        int r0 = p0 + XOR1_I(p1);                                              \
        int r2 = p2 + XOR1_I(p3);                                              \
        int f0 = r0 + XOR2_I(r2);   /* full K sum, OWN gate q (exact) */       \
        float pre = (float)f0 * dqf + bf16_to_f32((unsigned short)(myp >> psh)); \
        float sg1 = frcp(1.f + fexp2(pre));                                    \
        float vv  = sg1 * vsc + voff;   /* lane0:i 1:f 2:tanh(g) 3:o */        \
        float mm  = vv * xor2_f(vv);    /* lane0: i*g */                       \
        float mx  = xor1_f(mm);         /* lane1 <- i*g */                     \
        float cn  = vv * c_st + mx;     /* lane1: f*c + i*g */                 \
        c_st = cn;                                                             \
        float th  = 2.f * frcp(1.f + fexp2(cn * CNEG)) - 1.f; /* lane1 */      \
        float hout = vv * xor2_f(th);   /* lane3: o*tanh(c) */                 \
        h_last = hout;                                                         \
        if (q == 3)                                                            \
            ((char*)(HWR))[j] = (char)__float2int_rn(hout * 127.f);            \
        __syncthreads();                                                       \
    }

    int* h0b = hq[0];
    int* h1b = hq[1];

    for (int t = 0; t < SEQ; t += 2) {
        LSTM_STEP(t,     prefA, h0b, h1b);   // even step: read buf0, write buf1
        LSTM_STEP(t + 1, prefB, h1b, h0b);   // odd  step: read buf1, write buf0
    }
#undef LSTM_STEP

    // Final outputs: h (lane3) then c (lane1), fp32 [64][256]
    if (q == 3) out[(size_t)b * 256 + j]         = h_last;
    if (q == 1) out[16384 + (size_t)b * 256 + j] = c_st;
}

// ---------------------------------------------------------------------------
// Launch
// ---------------------------------------------------------------------------
extern "C" void kernel_launch(void* const* d_in, const int* in_sizes, int n_in,
                              void* d_out, int out_size, void* d_ws, size_t ws_size,
                              hipStream_t stream) {
    (void)in_sizes; (void)n_in; (void)out_size; (void)ws_size;
    const float* x = (const float*)d_in[0];

    // Workspace carve (~269.2 MB)
    char* ws = (char*)d_ws;
    const size_t PSW_BYTES = (size_t)SEQ * 4 * 8192 * 4;    // 268,435,456 (dwords)
    uint32_t*       Psw     = (uint32_t*)ws;
    unsigned short* WT      = (unsigned short*)(ws + PSW_BYTES);           // 512 KB
    int*            Wh8     = (int*)(ws + PSW_BYTES + 524288);             // 256 KB (Wp2)
    float*          biascat = (float*)(ws + PSW_BYTES + 524288 + 262144);  // 4 KB

    PrepArgs pa;
    pa.Wi[0] = (const float*)d_in[1];  pa.Wh[0] = (const float*)d_in[2];
    pa.bi[0] = (const float*)d_in[3];  pa.bh[0] = (const float*)d_in[4];
    pa.Wi[1] = (const float*)d_in[5];  pa.Wh[1] = (const float*)d_in[6];
    pa.bi[1] = (const float*)d_in[7];  pa.bh[1] = (const float*)d_in[8];
    pa.Wi[2] = (const float*)d_in[9];  pa.Wh[2] = (const float*)d_in[10];
    pa.bi[2] = (const float*)d_in[11]; pa.bh[2] = (const float*)d_in[12];
    pa.Wi[3] = (const float*)d_in[13]; pa.Wh[3] = (const float*)d_in[14];
    pa.bi[3] = (const float*)d_in[15]; pa.bh[3] = (const float*)d_in[16];
    pa.WT = WT; pa.biascat = biascat; pa.Wh8 = Wh8;
    prep_kernel<<<1284, 256, 0, stream>>>(pa);

    proj_kernel<<<4096, 256, 0, stream>>>(x, WT, biascat, Psw);

    recur_kernel<<<64, 1024, 0, stream>>>((const int*)Wh8, Psw, (float*)d_out);
}